// Round 1
// baseline (945.013 us; speedup 1.0000x reference)
//
#include <hip/hip_runtime.h>

#define NNODES 20000
#define EEDGES 320000
#define DD     256
#define NEG_SLOPE 0.2f

// ---------------- CSR build ----------------

__global__ void zero_ints_k(int* __restrict__ p, int n) {
    int i = blockIdx.x * 256 + threadIdx.x;
    if (i < n) p[i] = 0;
}

__global__ void hist_k(const int* __restrict__ dst, int* __restrict__ rowptr) {
    int i = blockIdx.x * 256 + threadIdx.x;
    if (i < EEDGES) atomicAdd(&rowptr[dst[i] + 1], 1);
}

// single-block inclusive scan of rowptr[1..NNODES]
__global__ __launch_bounds__(256) void scan_k(int* __restrict__ rowptr) {
    __shared__ int buf[256];
    __shared__ int carry;
    if (threadIdx.x == 0) carry = 0;
    __syncthreads();
    for (int base = 1; base <= NNODES; base += 256) {
        int idx = base + (int)threadIdx.x;
        int v = (idx <= NNODES) ? rowptr[idx] : 0;
        __syncthreads();
        buf[threadIdx.x] = v;
        __syncthreads();
        for (int off = 1; off < 256; off <<= 1) {
            int t = (threadIdx.x >= (unsigned)off) ? buf[threadIdx.x - off] : 0;
            __syncthreads();
            buf[threadIdx.x] += t;
            __syncthreads();
        }
        if (idx <= NNODES) rowptr[idx] = carry + buf[threadIdx.x];
        __syncthreads();
        if (threadIdx.x == 0) carry += buf[255];
        __syncthreads();
    }
}

__global__ void copy_cursor_k(const int* __restrict__ rowptr, int* __restrict__ cursor) {
    int i = blockIdx.x * 256 + threadIdx.x;
    if (i < NNODES) cursor[i] = rowptr[i];
}

__global__ void scatter_k(const int* __restrict__ src, const int* __restrict__ dst,
                          int* __restrict__ cursor, int* __restrict__ colsrc) {
    int i = blockIdx.x * 256 + threadIdx.x;
    if (i < EEDGES) {
        int d = dst[i];
        int pos = atomicAdd(&cursor[d], 1);
        colsrc[pos] = src[i];
    }
}

// ---------------- W3 folding: concat(h,h)@W3 == relu(h)@(W3_top+W3_bot) ----------------

__global__ void w3sum_k(const float* __restrict__ W3, float* __restrict__ wsum) {
    int i = blockIdx.x * 256 + threadIdx.x;
    if (i < DD * DD) wsum[i] = W3[i] + W3[i + DD * DD];
}

// ---------------- fp32 GEMM: C[M,256] = act(A)[M,256] @ B[256,256] ----------------
// tile 128 rows x 64 cols, 256 threads, 8x4 micro-tile

template<bool RELU_A>
__global__ __launch_bounds__(256) void gemm_k(const float* __restrict__ A,
                                              const float* __restrict__ B,
                                              float* __restrict__ C, int M) {
    __shared__ float As[16][128];
    __shared__ float Bs[16][64];
    const int t  = threadIdx.x;
    const int tx = t & 15;   // col group (4 cols)
    const int ty = t >> 4;   // row group (8 rows)
    const int rowBase = blockIdx.y * 128;
    const int colBase = blockIdx.x * 64;

    float acc[8][4];
#pragma unroll
    for (int i = 0; i < 8; ++i)
#pragma unroll
        for (int j = 0; j < 4; ++j) acc[i][j] = 0.f;

    const int arow = t >> 2;         // 0..63
    const int ac   = (t & 3) * 4;    // k offset 0..12
    const int brow = t >> 4;         // 0..15
    const int bcol = (t & 15) * 4;

    for (int k0 = 0; k0 < DD; k0 += 16) {
        int r0 = rowBase + arow;
        int r1 = r0 + 64;
        float4 a0 = make_float4(0.f, 0.f, 0.f, 0.f);
        float4 a1 = make_float4(0.f, 0.f, 0.f, 0.f);
        if (r0 < M) a0 = *(const float4*)(A + (size_t)r0 * DD + k0 + ac);
        if (r1 < M) a1 = *(const float4*)(A + (size_t)r1 * DD + k0 + ac);
        if (RELU_A) {
            a0.x = fmaxf(a0.x, 0.f); a0.y = fmaxf(a0.y, 0.f);
            a0.z = fmaxf(a0.z, 0.f); a0.w = fmaxf(a0.w, 0.f);
            a1.x = fmaxf(a1.x, 0.f); a1.y = fmaxf(a1.y, 0.f);
            a1.z = fmaxf(a1.z, 0.f); a1.w = fmaxf(a1.w, 0.f);
        }
        float4 bv = *(const float4*)(B + (size_t)(k0 + brow) * DD + colBase + bcol);
        __syncthreads();
        As[ac + 0][arow] = a0.x; As[ac + 1][arow] = a0.y;
        As[ac + 2][arow] = a0.z; As[ac + 3][arow] = a0.w;
        As[ac + 0][arow + 64] = a1.x; As[ac + 1][arow + 64] = a1.y;
        As[ac + 2][arow + 64] = a1.z; As[ac + 3][arow + 64] = a1.w;
        *(float4*)&Bs[brow][bcol] = bv;
        __syncthreads();
#pragma unroll
        for (int kk = 0; kk < 16; ++kk) {
            float4 aA = *(const float4*)&As[kk][ty * 8];
            float4 aB = *(const float4*)&As[kk][ty * 8 + 4];
            float4 b4 = *(const float4*)&Bs[kk][tx * 4];
            float a[8] = {aA.x, aA.y, aA.z, aA.w, aB.x, aB.y, aB.z, aB.w};
            float b[4] = {b4.x, b4.y, b4.z, b4.w};
#pragma unroll
            for (int i = 0; i < 8; ++i)
#pragma unroll
                for (int j = 0; j < 4; ++j)
                    acc[i][j] = fmaf(a[i], b[j], acc[i][j]);
        }
    }
#pragma unroll
    for (int i = 0; i < 8; ++i) {
        int r = rowBase + ty * 8 + i;
        if (r < M) {
            float4 o = make_float4(acc[i][0], acc[i][1], acc[i][2], acc[i][3]);
            *(float4*)(C + (size_t)r * DD + colBase + tx * 4) = o;
        }
    }
}

// ---------------- per-node attention dots: es[n]=hw[n]@asrc, ed[n]=hw[n]@adst ----------------

__global__ __launch_bounds__(256) void dots_k(const float* __restrict__ hw,
                                              const float* __restrict__ asrc,
                                              const float* __restrict__ adst,
                                              float* __restrict__ es, float* __restrict__ ed) {
    int wave = threadIdx.x >> 6;
    int lane = threadIdx.x & 63;
    int node = blockIdx.x * 4 + wave;
    if (node >= NNODES) return;
    float4 v = *(const float4*)(hw + (size_t)node * DD + lane * 4);
    float4 a = *(const float4*)(asrc + lane * 4);
    float4 b = *(const float4*)(adst + lane * 4);
    float s = v.x * a.x + v.y * a.y + v.z * a.z + v.w * a.w;
    float d = v.x * b.x + v.y * b.y + v.z * b.z + v.w * b.w;
#pragma unroll
    for (int off = 32; off; off >>= 1) {
        s += __shfl_xor(s, off);
        d += __shfl_xor(d, off);
    }
    if (lane == 0) { es[node] = s; ed[node] = d; }
}

// ---------------- fused segment softmax + weighted aggregation (one wave per node) ----------------

__global__ __launch_bounds__(256) void gat_agg_k(const float* __restrict__ hw,
                                                 const float* __restrict__ es,
                                                 const float* __restrict__ ed,
                                                 const int* __restrict__ rowptr,
                                                 const int* __restrict__ colsrc,
                                                 float* __restrict__ ealpha,
                                                 const float* __restrict__ bias,
                                                 float* __restrict__ hout) {
    int wave = threadIdx.x >> 6;
    int lane = threadIdx.x & 63;
    int node = blockIdx.x * 4 + wave;
    if (node >= NNODES) return;
    int start = rowptr[node], end = rowptr[node + 1];
    float edd = ed[node];

    // phase A: max of leaky_relu scores over incoming edges
    float mx = -INFINITY;
    for (int j = start + lane; j < end; j += 64) {
        float e = es[colsrc[j]] + edd;
        e = e > 0.f ? e : NEG_SLOPE * e;
        mx = fmaxf(mx, e);
    }
#pragma unroll
    for (int off = 32; off; off >>= 1) mx = fmaxf(mx, __shfl_xor(mx, off));

    // phase B: exp + denom (store numerators to scratch)
    float sum = 0.f;
    for (int j = start + lane; j < end; j += 64) {
        float e = es[colsrc[j]] + edd;
        e = e > 0.f ? e : NEG_SLOPE * e;
        float ee = expf(e - mx);
        ealpha[j] = ee;
        sum += ee;
    }
#pragma unroll
    for (int off = 32; off; off >>= 1) sum += __shfl_xor(sum, off);
    float inv = (end > start) ? 1.f / sum : 0.f;

    // phase C: out[node,:] = sum_j alpha_j * hw[src_j,:]  (lanes over D)
    float4 acc = make_float4(0.f, 0.f, 0.f, 0.f);
    for (int j = start; j < end; ++j) {
        int s = colsrc[j];
        float w = ealpha[j] * inv;
        float4 v = *(const float4*)(hw + (size_t)s * DD + lane * 4);
        acc.x = fmaf(w, v.x, acc.x); acc.y = fmaf(w, v.y, acc.y);
        acc.z = fmaf(w, v.z, acc.z); acc.w = fmaf(w, v.w, acc.w);
    }
    float4 b4 = *(const float4*)(bias + lane * 4);
    acc.x += b4.x; acc.y += b4.y; acc.z += b4.z; acc.w += b4.w;
    *(float4*)(hout + (size_t)node * DD + lane * 4) = acc;
}

// ---------------- driver ----------------

extern "C" void kernel_launch(void* const* d_in, const int* in_sizes, int n_in,
                              void* d_out, int out_size, void* d_ws, size_t ws_size,
                              hipStream_t stream) {
    const float* x     = (const float*)d_in[0];
    const int*   ei    = (const int*)d_in[1];     // [2,E]: first E = src, next E = dst
    const float* W1    = (const float*)d_in[2];
    const float* W2    = (const float*)d_in[3];
    const float* Ws    = (const float*)d_in[4];   // [6,256,256]
    const float* a_src = (const float*)d_in[5];   // [6,256]
    const float* a_dst = (const float*)d_in[6];
    const float* bias  = (const float*)d_in[7];   // [6,256]
    const float* W3    = (const float*)d_in[8];   // [512,256]
    float* out = (float*)d_out;

    const int* src = ei;
    const int* dst = ei + EEDGES;

    // workspace carve-up
    float* bufA   = (float*)d_ws;                      // N*D
    float* bufB   = bufA + (size_t)NNODES * DD;        // N*D
    float* es     = bufB + (size_t)NNODES * DD;        // N
    float* edv    = es + NNODES;                       // N
    float* ealpha = edv + NNODES;                      // E
    float* w3s    = ealpha + EEDGES;                   // 256*256
    int*   rowptr = (int*)(w3s + DD * DD);             // N+1
    int*   cursor = rowptr + (NNODES + 1);             // N
    int*   colsrc = cursor + NNODES;                   // E

    // --- CSR build (per call; harness poisons ws) ---
    zero_ints_k<<<(NNODES + 1 + 255) / 256, 256, 0, stream>>>(rowptr, NNODES + 1);
    hist_k<<<(EEDGES + 255) / 256, 256, 0, stream>>>(dst, rowptr);
    scan_k<<<1, 256, 0, stream>>>(rowptr);
    copy_cursor_k<<<(NNODES + 255) / 256, 256, 0, stream>>>(rowptr, cursor);
    scatter_k<<<(EEDGES + 255) / 256, 256, 0, stream>>>(src, dst, cursor, colsrc);
    w3sum_k<<<(DD * DD + 255) / 256, 256, 0, stream>>>(W3, w3s);

    dim3 ggrid(DD / 64, (NNODES + 127) / 128);
    const int nodeBlocks = (NNODES + 3) / 4;

    // h = (x @ W1) @ W2
    gemm_k<false><<<ggrid, 256, 0, stream>>>(x, W1, bufA, NNODES);
    gemm_k<false><<<ggrid, 256, 0, stream>>>(bufA, W2, bufB, NNODES);

    // 6 GAT layers; cur lives in bufB, hw in bufA each layer
    for (int l = 0; l < 6; ++l) {
        gemm_k<false><<<ggrid, 256, 0, stream>>>(bufB, Ws + (size_t)l * DD * DD, bufA, NNODES);
        dots_k<<<nodeBlocks, 256, 0, stream>>>(bufA, a_src + (size_t)l * DD, a_dst + (size_t)l * DD, es, edv);
        gat_agg_k<<<nodeBlocks, 256, 0, stream>>>(bufA, es, edv, rowptr, colsrc, ealpha,
                                                  bias + (size_t)l * DD, bufB);
    }

    // out = relu(h) @ (W3_top + W3_bot)
    gemm_k<true><<<ggrid, 256, 0, stream>>>(bufB, w3s, out, NNODES);
}

// Round 2
// 924.997 us; speedup vs baseline: 1.0216x; 1.0216x over previous
//
#include <hip/hip_runtime.h>

#define NNODES 20000
#define EEDGES 320000
#define DD     256
#define NEG_SLOPE 0.2f
#define SCAN_BLOCKS ((NNODES + 255) / 256)

// ---------------- CSR build ----------------

__global__ void zero_ints_k(int* __restrict__ p, int n) {
    int i = blockIdx.x * 256 + threadIdx.x;
    if (i < n) p[i] = 0;
}

__global__ void hist_k(const int* __restrict__ dst, int* __restrict__ rowptr) {
    int i = blockIdx.x * 256 + threadIdx.x;
    if (i < EEDGES) atomicAdd(&rowptr[dst[i] + 1], 1);
}

// hierarchical scan: per-block inclusive scan + block sums
__global__ __launch_bounds__(256) void scan1_k(int* __restrict__ rowptr, int* __restrict__ bsums) {
    __shared__ int buf[256];
    int idx = blockIdx.x * 256 + threadIdx.x;
    int v = (idx < NNODES) ? rowptr[idx + 1] : 0;
    buf[threadIdx.x] = v;
    __syncthreads();
#pragma unroll
    for (int off = 1; off < 256; off <<= 1) {
        int t = (threadIdx.x >= (unsigned)off) ? buf[threadIdx.x - off] : 0;
        __syncthreads();
        buf[threadIdx.x] += t;
        __syncthreads();
    }
    if (idx < NNODES) rowptr[idx + 1] = buf[threadIdx.x];
    if (threadIdx.x == 255) bsums[blockIdx.x] = buf[255];
}

__global__ __launch_bounds__(128) void scan2_k(int* __restrict__ bsums) {
    __shared__ int buf[128];
    int v = (threadIdx.x < SCAN_BLOCKS) ? bsums[threadIdx.x] : 0;
    buf[threadIdx.x] = v;
    __syncthreads();
#pragma unroll
    for (int off = 1; off < 128; off <<= 1) {
        int t = (threadIdx.x >= (unsigned)off) ? buf[threadIdx.x - off] : 0;
        __syncthreads();
        buf[threadIdx.x] += t;
        __syncthreads();
    }
    if (threadIdx.x < SCAN_BLOCKS) bsums[threadIdx.x] = buf[threadIdx.x];
}

__global__ void scan3_k(int* __restrict__ rowptr, const int* __restrict__ bsums) {
    int idx = blockIdx.x * 256 + threadIdx.x;
    if (blockIdx.x > 0 && idx < NNODES) rowptr[idx + 1] += bsums[blockIdx.x - 1];
}

__global__ void copy_cursor_k(const int* __restrict__ rowptr, int* __restrict__ cursor) {
    int i = blockIdx.x * 256 + threadIdx.x;
    if (i < NNODES) cursor[i] = rowptr[i];
}

__global__ void scatter_k(const int* __restrict__ src, const int* __restrict__ dst,
                          int* __restrict__ cursor, int* __restrict__ colsrc) {
    int i = blockIdx.x * 256 + threadIdx.x;
    if (i < EEDGES) {
        int d = dst[i];
        int pos = atomicAdd(&cursor[d], 1);
        colsrc[pos] = src[i];
    }
}

// ---------------- W3 folding: concat(h,h)@W3 == relu(h)@(W3_top+W3_bot) ----------------

__global__ void w3sum_k(const float* __restrict__ W3, float* __restrict__ wsum) {
    int i = blockIdx.x * 256 + threadIdx.x;
    if (i < DD * DD) wsum[i] = W3[i] + W3[i + DD * DD];
}

// ---------------- fp32 GEMM: C[M,256] = act(A)[M,256] @ B[256,256] ----------------
// tile 128 rows x 128 cols, 256 threads, 8x8 micro-tile (cols split tx*4 and tx*4+64
// so Bs reads are 2-way bank aliased = free; As reads conflict-free)

template<bool RELU_A>
__global__ __launch_bounds__(256) void gemm_k(const float* __restrict__ A,
                                              const float* __restrict__ B,
                                              float* __restrict__ C, int M) {
    __shared__ float As[16][128];
    __shared__ float Bs[16][128];
    const int t  = threadIdx.x;
    const int tx = t & 15;   // col group
    const int ty = t >> 4;   // row group (8 rows)
    const int rowBase = blockIdx.y * 128;
    const int colBase = blockIdx.x * 128;

    float acc[8][8];
#pragma unroll
    for (int i = 0; i < 8; ++i)
#pragma unroll
        for (int j = 0; j < 8; ++j) acc[i][j] = 0.f;

    const int ar = t >> 2;          // 0..63
    const int ac = (t & 3) * 4;     // 0..12
    const int br = t >> 5;          // 0..7
    const int bc = (t & 31) * 4;    // 0..124

    for (int k0 = 0; k0 < DD; k0 += 16) {
        int r0 = rowBase + ar;
        int r1 = r0 + 64;
        float4 a0 = make_float4(0.f, 0.f, 0.f, 0.f);
        float4 a1 = make_float4(0.f, 0.f, 0.f, 0.f);
        if (r0 < M) a0 = *(const float4*)(A + (size_t)r0 * DD + k0 + ac);
        if (r1 < M) a1 = *(const float4*)(A + (size_t)r1 * DD + k0 + ac);
        if (RELU_A) {
            a0.x = fmaxf(a0.x, 0.f); a0.y = fmaxf(a0.y, 0.f);
            a0.z = fmaxf(a0.z, 0.f); a0.w = fmaxf(a0.w, 0.f);
            a1.x = fmaxf(a1.x, 0.f); a1.y = fmaxf(a1.y, 0.f);
            a1.z = fmaxf(a1.z, 0.f); a1.w = fmaxf(a1.w, 0.f);
        }
        float4 b0 = *(const float4*)(B + (size_t)(k0 + br) * DD + colBase + bc);
        float4 b1 = *(const float4*)(B + (size_t)(k0 + br + 8) * DD + colBase + bc);
        __syncthreads();
        As[ac + 0][ar] = a0.x; As[ac + 1][ar] = a0.y;
        As[ac + 2][ar] = a0.z; As[ac + 3][ar] = a0.w;
        As[ac + 0][ar + 64] = a1.x; As[ac + 1][ar + 64] = a1.y;
        As[ac + 2][ar + 64] = a1.z; As[ac + 3][ar + 64] = a1.w;
        *(float4*)&Bs[br][bc] = b0;
        *(float4*)&Bs[br + 8][bc] = b1;
        __syncthreads();
#pragma unroll
        for (int kk = 0; kk < 16; ++kk) {
            float4 aA = *(const float4*)&As[kk][ty * 8];
            float4 aB = *(const float4*)&As[kk][ty * 8 + 4];
            float4 bA = *(const float4*)&Bs[kk][tx * 4];
            float4 bB = *(const float4*)&Bs[kk][tx * 4 + 64];
            float a[8] = {aA.x, aA.y, aA.z, aA.w, aB.x, aB.y, aB.z, aB.w};
            float b[8] = {bA.x, bA.y, bA.z, bA.w, bB.x, bB.y, bB.z, bB.w};
#pragma unroll
            for (int i = 0; i < 8; ++i)
#pragma unroll
                for (int j = 0; j < 8; ++j)
                    acc[i][j] = fmaf(a[i], b[j], acc[i][j]);
        }
    }
#pragma unroll
    for (int i = 0; i < 8; ++i) {
        int r = rowBase + ty * 8 + i;
        if (r < M) {
            float4 o0 = make_float4(acc[i][0], acc[i][1], acc[i][2], acc[i][3]);
            float4 o1 = make_float4(acc[i][4], acc[i][5], acc[i][6], acc[i][7]);
            *(float4*)(C + (size_t)r * DD + colBase + tx * 4) = o0;
            *(float4*)(C + (size_t)r * DD + colBase + tx * 4 + 64) = o1;
        }
    }
}

// ---------------- per-node attention dots: es[n]=hw[n]@asrc, ed[n]=hw[n]@adst ----------------

__global__ __launch_bounds__(256) void dots_k(const float* __restrict__ hw,
                                              const float* __restrict__ asrc,
                                              const float* __restrict__ adst,
                                              float* __restrict__ es, float* __restrict__ ed) {
    int wave = threadIdx.x >> 6;
    int lane = threadIdx.x & 63;
    int node = blockIdx.x * 4 + wave;
    if (node >= NNODES) return;
    float4 v = *(const float4*)(hw + (size_t)node * DD + lane * 4);
    float4 a = *(const float4*)(asrc + lane * 4);
    float4 b = *(const float4*)(adst + lane * 4);
    float s = v.x * a.x + v.y * a.y + v.z * a.z + v.w * a.w;
    float d = v.x * b.x + v.y * b.y + v.z * b.z + v.w * b.w;
#pragma unroll
    for (int off = 32; off; off >>= 1) {
        s += __shfl_xor(s, off);
        d += __shfl_xor(d, off);
    }
    if (lane == 0) { es[node] = s; ed[node] = d; }
}

// ---------------- fused segment softmax + weighted aggregation (one wave per node) ----------------

__global__ __launch_bounds__(256) void gat_agg_k(const float* __restrict__ hw,
                                                 const float* __restrict__ es,
                                                 const float* __restrict__ ed,
                                                 const int* __restrict__ rowptr,
                                                 const int* __restrict__ colsrc,
                                                 float* __restrict__ ealpha,
                                                 const float* __restrict__ bias,
                                                 float* __restrict__ hout) {
    int wave = threadIdx.x >> 6;
    int lane = threadIdx.x & 63;
    int node = blockIdx.x * 4 + wave;
    if (node >= NNODES) return;
    int start = rowptr[node], end = rowptr[node + 1];
    float edd = ed[node];

    // phase A: max of leaky_relu scores over incoming edges
    float mx = -INFINITY;
    for (int j = start + lane; j < end; j += 64) {
        float e = es[colsrc[j]] + edd;
        e = e > 0.f ? e : NEG_SLOPE * e;
        mx = fmaxf(mx, e);
    }
#pragma unroll
    for (int off = 32; off; off >>= 1) mx = fmaxf(mx, __shfl_xor(mx, off));

    // phase B: exp + denom (store numerators to scratch)
    float sum = 0.f;
    for (int j = start + lane; j < end; j += 64) {
        float e = es[colsrc[j]] + edd;
        e = e > 0.f ? e : NEG_SLOPE * e;
        float ee = expf(e - mx);
        ealpha[j] = ee;
        sum += ee;
    }
#pragma unroll
    for (int off = 32; off; off >>= 1) sum += __shfl_xor(sum, off);
    float inv = (end > start) ? 1.f / sum : 0.f;

    // phase C: out[node,:] = sum_j alpha_j * hw[src_j,:]  (lanes over D)
    float4 acc = make_float4(0.f, 0.f, 0.f, 0.f);
    for (int j = start; j < end; ++j) {
        int s = colsrc[j];
        float w = ealpha[j] * inv;
        float4 v = *(const float4*)(hw + (size_t)s * DD + lane * 4);
        acc.x = fmaf(w, v.x, acc.x); acc.y = fmaf(w, v.y, acc.y);
        acc.z = fmaf(w, v.z, acc.z); acc.w = fmaf(w, v.w, acc.w);
    }
    float4 b4 = *(const float4*)(bias + lane * 4);
    acc.x += b4.x; acc.y += b4.y; acc.z += b4.z; acc.w += b4.w;
    *(float4*)(hout + (size_t)node * DD + lane * 4) = acc;
}

// ---------------- driver ----------------

extern "C" void kernel_launch(void* const* d_in, const int* in_sizes, int n_in,
                              void* d_out, int out_size, void* d_ws, size_t ws_size,
                              hipStream_t stream) {
    const float* x     = (const float*)d_in[0];
    const int*   ei    = (const int*)d_in[1];     // [2,E]: first E = src, next E = dst
    const float* W1    = (const float*)d_in[2];
    const float* W2    = (const float*)d_in[3];
    const float* Ws    = (const float*)d_in[4];   // [6,256,256]
    const float* a_src = (const float*)d_in[5];   // [6,256]
    const float* a_dst = (const float*)d_in[6];
    const float* bias  = (const float*)d_in[7];   // [6,256]
    const float* W3    = (const float*)d_in[8];   // [512,256]
    float* out = (float*)d_out;

    const int* src = ei;
    const int* dst = ei + EEDGES;

    // workspace carve-up
    float* bufA   = (float*)d_ws;                      // N*D
    float* bufB   = bufA + (size_t)NNODES * DD;        // N*D
    float* es     = bufB + (size_t)NNODES * DD;        // N
    float* edv    = es + NNODES;                       // N
    float* ealpha = edv + NNODES;                      // E
    float* w3s    = ealpha + EEDGES;                   // 256*256
    int*   rowptr = (int*)(w3s + DD * DD);             // N+1
    int*   cursor = rowptr + (NNODES + 1);             // N
    int*   colsrc = cursor + NNODES;                   // E
    int*   bsums  = colsrc + EEDGES;                   // SCAN_BLOCKS

    // --- CSR build (per call; harness poisons ws) ---
    zero_ints_k<<<(NNODES + 1 + 255) / 256, 256, 0, stream>>>(rowptr, NNODES + 1);
    hist_k<<<(EEDGES + 255) / 256, 256, 0, stream>>>(dst, rowptr);
    scan1_k<<<SCAN_BLOCKS, 256, 0, stream>>>(rowptr, bsums);
    scan2_k<<<1, 128, 0, stream>>>(bsums);
    scan3_k<<<SCAN_BLOCKS, 256, 0, stream>>>(rowptr, bsums);
    copy_cursor_k<<<(NNODES + 255) / 256, 256, 0, stream>>>(rowptr, cursor);
    scatter_k<<<(EEDGES + 255) / 256, 256, 0, stream>>>(src, dst, cursor, colsrc);
    w3sum_k<<<(DD * DD + 255) / 256, 256, 0, stream>>>(W3, w3s);

    dim3 ggrid(DD / 128, (NNODES + 127) / 128);
    const int nodeBlocks = (NNODES + 3) / 4;

    // h = (x @ W1) @ W2
    gemm_k<false><<<ggrid, 256, 0, stream>>>(x, W1, bufA, NNODES);
    gemm_k<false><<<ggrid, 256, 0, stream>>>(bufA, W2, bufB, NNODES);

    // 6 GAT layers; cur lives in bufB, hw in bufA each layer
    for (int l = 0; l < 6; ++l) {
        gemm_k<false><<<ggrid, 256, 0, stream>>>(bufB, Ws + (size_t)l * DD * DD, bufA, NNODES);
        dots_k<<<nodeBlocks, 256, 0, stream>>>(bufA, a_src + (size_t)l * DD, a_dst + (size_t)l * DD, es, edv);
        gat_agg_k<<<nodeBlocks, 256, 0, stream>>>(bufA, es, edv, rowptr, colsrc, ealpha,
                                                  bias + (size_t)l * DD, bufB);
    }

    // out = relu(h) @ (W3_top + W3_bot)
    gemm_k<true><<<ggrid, 256, 0, stream>>>(bufB, w3s, out, NNODES);
}

// Round 3
// 869.508 us; speedup vs baseline: 1.0868x; 1.0638x over previous
//
#include <hip/hip_runtime.h>

#define NNODES 20000
#define EEDGES 320000
#define DD     256
#define NEG_SLOPE 0.2f
#define SCAN_BLOCKS ((NNODES + 255) / 256)

// ---------------- CSR build ----------------

__global__ void zero_ints_k(int* __restrict__ p, int n) {
    int i = blockIdx.x * 256 + threadIdx.x;
    if (i < n) p[i] = 0;
}

__global__ void hist_k(const int* __restrict__ dst, int* __restrict__ rowptr) {
    int i = blockIdx.x * 256 + threadIdx.x;
    if (i < EEDGES) atomicAdd(&rowptr[dst[i] + 1], 1);
}

// hierarchical scan: per-block inclusive scan + block sums
__global__ __launch_bounds__(256) void scan1_k(int* __restrict__ rowptr, int* __restrict__ bsums) {
    __shared__ int buf[256];
    int idx = blockIdx.x * 256 + threadIdx.x;
    int v = (idx < NNODES) ? rowptr[idx + 1] : 0;
    buf[threadIdx.x] = v;
    __syncthreads();
#pragma unroll
    for (int off = 1; off < 256; off <<= 1) {
        int t = (threadIdx.x >= (unsigned)off) ? buf[threadIdx.x - off] : 0;
        __syncthreads();
        buf[threadIdx.x] += t;
        __syncthreads();
    }
    if (idx < NNODES) rowptr[idx + 1] = buf[threadIdx.x];
    if (threadIdx.x == 255) bsums[blockIdx.x] = buf[255];
}

__global__ __launch_bounds__(128) void scan2_k(int* __restrict__ bsums) {
    __shared__ int buf[128];
    int v = (threadIdx.x < SCAN_BLOCKS) ? bsums[threadIdx.x] : 0;
    buf[threadIdx.x] = v;
    __syncthreads();
#pragma unroll
    for (int off = 1; off < 128; off <<= 1) {
        int t = (threadIdx.x >= (unsigned)off) ? buf[threadIdx.x - off] : 0;
        __syncthreads();
        buf[threadIdx.x] += t;
        __syncthreads();
    }
    if (threadIdx.x < SCAN_BLOCKS) bsums[threadIdx.x] = buf[threadIdx.x];
}

__global__ void scan3_k(int* __restrict__ rowptr, const int* __restrict__ bsums) {
    int idx = blockIdx.x * 256 + threadIdx.x;
    if (blockIdx.x > 0 && idx < NNODES) rowptr[idx + 1] += bsums[blockIdx.x - 1];
}

__global__ void copy_cursor_k(const int* __restrict__ rowptr, int* __restrict__ cursor) {
    int i = blockIdx.x * 256 + threadIdx.x;
    if (i < NNODES) cursor[i] = rowptr[i];
}

__global__ void scatter_k(const int* __restrict__ src, const int* __restrict__ dst,
                          int* __restrict__ cursor, int* __restrict__ colsrc) {
    int i = blockIdx.x * 256 + threadIdx.x;
    if (i < EEDGES) {
        int d = dst[i];
        int pos = atomicAdd(&cursor[d], 1);
        colsrc[pos] = src[i];
    }
}

// ---------------- W3 folding: concat(h,h)@W3 == relu(h)@(W3_top+W3_bot) ----------------

__global__ void w3sum_k(const float* __restrict__ W3, float* __restrict__ wsum) {
    int i = blockIdx.x * 256 + threadIdx.x;
    if (i < DD * DD) wsum[i] = W3[i] + W3[i + DD * DD];
}

// ---------------- fp32 GEMM: C[M,256] = act(A)[M,256] @ B[256,256] ----------------
// tile 64 rows x 128 cols, 128 threads, 8x8 micro-tile, software-pipelined
// global loads. As padded to pitch 132 -> transpose writes are 2-way (free).

template<bool RELU_A>
__global__ __launch_bounds__(128) void gemm_k(const float* __restrict__ A,
                                              const float* __restrict__ B,
                                              float* __restrict__ C, int M) {
    __shared__ float As[16][132];
    __shared__ float Bs[16][128];
    const int t  = threadIdx.x;
    const int tx = t & 15;   // col group
    const int ty = t >> 4;   // row group 0..7 (8 rows each)
    const int rowBase = blockIdx.y * 64;
    const int colBase = blockIdx.x * 128;

    float acc[8][8];
#pragma unroll
    for (int i = 0; i < 8; ++i)
#pragma unroll
        for (int j = 0; j < 8; ++j) acc[i][j] = 0.f;

    const int ar = t >> 1;          // 0..63  (A row within tile)
    const int ac = (t & 1) * 8;     // 0 or 8 (A k-offset)
    const int br = t >> 5;          // 0..3   (B k-row group)
    const int bc = (t & 31) * 4;    // 0..124 (B col)
    const int arow = rowBase + ar;

    float4 a0, a1, b0, b1, b2, b3;
    // prologue: load k0 = 0
    {
        a0 = make_float4(0.f, 0.f, 0.f, 0.f);
        a1 = make_float4(0.f, 0.f, 0.f, 0.f);
        if (arow < M) {
            a0 = *(const float4*)(A + (size_t)arow * DD + ac);
            a1 = *(const float4*)(A + (size_t)arow * DD + ac + 4);
        }
        b0 = *(const float4*)(B + (size_t)(br     ) * DD + colBase + bc);
        b1 = *(const float4*)(B + (size_t)(br +  4) * DD + colBase + bc);
        b2 = *(const float4*)(B + (size_t)(br +  8) * DD + colBase + bc);
        b3 = *(const float4*)(B + (size_t)(br + 12) * DD + colBase + bc);
    }

    for (int k0 = 0; k0 < DD; k0 += 16) {
        if (RELU_A) {
            a0.x = fmaxf(a0.x, 0.f); a0.y = fmaxf(a0.y, 0.f);
            a0.z = fmaxf(a0.z, 0.f); a0.w = fmaxf(a0.w, 0.f);
            a1.x = fmaxf(a1.x, 0.f); a1.y = fmaxf(a1.y, 0.f);
            a1.z = fmaxf(a1.z, 0.f); a1.w = fmaxf(a1.w, 0.f);
        }
        __syncthreads();
        As[ac + 0][ar] = a0.x; As[ac + 1][ar] = a0.y;
        As[ac + 2][ar] = a0.z; As[ac + 3][ar] = a0.w;
        As[ac + 4][ar] = a1.x; As[ac + 5][ar] = a1.y;
        As[ac + 6][ar] = a1.z; As[ac + 7][ar] = a1.w;
        *(float4*)&Bs[br     ][bc] = b0;
        *(float4*)&Bs[br +  4][bc] = b1;
        *(float4*)&Bs[br +  8][bc] = b2;
        *(float4*)&Bs[br + 12][bc] = b3;
        __syncthreads();

        // prefetch next slab (overlaps with the FMA block below)
        if (k0 + 16 < DD) {
            int kn = k0 + 16;
            if (arow < M) {
                a0 = *(const float4*)(A + (size_t)arow * DD + kn + ac);
                a1 = *(const float4*)(A + (size_t)arow * DD + kn + ac + 4);
            }
            b0 = *(const float4*)(B + (size_t)(kn + br     ) * DD + colBase + bc);
            b1 = *(const float4*)(B + (size_t)(kn + br +  4) * DD + colBase + bc);
            b2 = *(const float4*)(B + (size_t)(kn + br +  8) * DD + colBase + bc);
            b3 = *(const float4*)(B + (size_t)(kn + br + 12) * DD + colBase + bc);
        }

#pragma unroll
        for (int kk = 0; kk < 16; ++kk) {
            float a[8], b[8];
            *(float2*)&a[0] = *(const float2*)&As[kk][ty * 8 + 0];
            *(float2*)&a[2] = *(const float2*)&As[kk][ty * 8 + 2];
            *(float2*)&a[4] = *(const float2*)&As[kk][ty * 8 + 4];
            *(float2*)&a[6] = *(const float2*)&As[kk][ty * 8 + 6];
            *(float4*)&b[0] = *(const float4*)&Bs[kk][tx * 4];
            *(float4*)&b[4] = *(const float4*)&Bs[kk][tx * 4 + 64];
#pragma unroll
            for (int i = 0; i < 8; ++i)
#pragma unroll
                for (int j = 0; j < 8; ++j)
                    acc[i][j] = fmaf(a[i], b[j], acc[i][j]);
        }
    }

#pragma unroll
    for (int i = 0; i < 8; ++i) {
        int r = rowBase + ty * 8 + i;
        if (r < M) {
            float4 o0 = make_float4(acc[i][0], acc[i][1], acc[i][2], acc[i][3]);
            float4 o1 = make_float4(acc[i][4], acc[i][5], acc[i][6], acc[i][7]);
            *(float4*)(C + (size_t)r * DD + colBase + tx * 4) = o0;
            *(float4*)(C + (size_t)r * DD + colBase + tx * 4 + 64) = o1;
        }
    }
}

// ---------------- per-node attention dots: es[n]=hw[n]@asrc, ed[n]=hw[n]@adst ----------------

__global__ __launch_bounds__(256) void dots_k(const float* __restrict__ hw,
                                              const float* __restrict__ asrc,
                                              const float* __restrict__ adst,
                                              float* __restrict__ es, float* __restrict__ ed) {
    int wave = threadIdx.x >> 6;
    int lane = threadIdx.x & 63;
    int node = blockIdx.x * 4 + wave;
    if (node >= NNODES) return;
    float4 v = *(const float4*)(hw + (size_t)node * DD + lane * 4);
    float4 a = *(const float4*)(asrc + lane * 4);
    float4 b = *(const float4*)(adst + lane * 4);
    float s = v.x * a.x + v.y * a.y + v.z * a.z + v.w * a.w;
    float d = v.x * b.x + v.y * b.y + v.z * b.z + v.w * b.w;
#pragma unroll
    for (int off = 32; off; off >>= 1) {
        s += __shfl_xor(s, off);
        d += __shfl_xor(d, off);
    }
    if (lane == 0) { es[node] = s; ed[node] = d; }
}

// ---------------- fused segment softmax + weighted aggregation (one wave per node) ----------------

__global__ __launch_bounds__(256) void gat_agg_k(const float* __restrict__ hw,
                                                 const float* __restrict__ es,
                                                 const float* __restrict__ ed,
                                                 const int* __restrict__ rowptr,
                                                 const int* __restrict__ colsrc,
                                                 float* __restrict__ ealpha,
                                                 const float* __restrict__ bias,
                                                 float* __restrict__ hout) {
    int wave = threadIdx.x >> 6;
    int lane = threadIdx.x & 63;
    int node = blockIdx.x * 4 + wave;
    if (node >= NNODES) return;
    int start = rowptr[node], end = rowptr[node + 1];
    float edd = ed[node];

    // phase A: max of leaky_relu scores over incoming edges
    float mx = -INFINITY;
    for (int j = start + lane; j < end; j += 64) {
        float e = es[colsrc[j]] + edd;
        e = e > 0.f ? e : NEG_SLOPE * e;
        mx = fmaxf(mx, e);
    }
#pragma unroll
    for (int off = 32; off; off >>= 1) mx = fmaxf(mx, __shfl_xor(mx, off));

    // phase B: exp + denom (store numerators to scratch)
    float sum = 0.f;
    for (int j = start + lane; j < end; j += 64) {
        float e = es[colsrc[j]] + edd;
        e = e > 0.f ? e : NEG_SLOPE * e;
        float ee = expf(e - mx);
        ealpha[j] = ee;
        sum += ee;
    }
#pragma unroll
    for (int off = 32; off; off >>= 1) sum += __shfl_xor(sum, off);
    float inv = (end > start) ? 1.f / sum : 0.f;

    // phase C: out[node,:] = sum_j alpha_j * hw[src_j,:]  (lanes over D)
    float4 acc = make_float4(0.f, 0.f, 0.f, 0.f);
    for (int j = start; j < end; ++j) {
        int s = colsrc[j];
        float w = ealpha[j] * inv;
        float4 v = *(const float4*)(hw + (size_t)s * DD + lane * 4);
        acc.x = fmaf(w, v.x, acc.x); acc.y = fmaf(w, v.y, acc.y);
        acc.z = fmaf(w, v.z, acc.z); acc.w = fmaf(w, v.w, acc.w);
    }
    float4 b4 = *(const float4*)(bias + lane * 4);
    acc.x += b4.x; acc.y += b4.y; acc.z += b4.z; acc.w += b4.w;
    *(float4*)(hout + (size_t)node * DD + lane * 4) = acc;
}

// ---------------- driver ----------------

extern "C" void kernel_launch(void* const* d_in, const int* in_sizes, int n_in,
                              void* d_out, int out_size, void* d_ws, size_t ws_size,
                              hipStream_t stream) {
    const float* x     = (const float*)d_in[0];
    const int*   ei    = (const int*)d_in[1];     // [2,E]: first E = src, next E = dst
    const float* W1    = (const float*)d_in[2];
    const float* W2    = (const float*)d_in[3];
    const float* Ws    = (const float*)d_in[4];   // [6,256,256]
    const float* a_src = (const float*)d_in[5];   // [6,256]
    const float* a_dst = (const float*)d_in[6];
    const float* bias  = (const float*)d_in[7];   // [6,256]
    const float* W3    = (const float*)d_in[8];   // [512,256]
    float* out = (float*)d_out;

    const int* src = ei;
    const int* dst = ei + EEDGES;

    // workspace carve-up
    float* bufA   = (float*)d_ws;                      // N*D
    float* bufB   = bufA + (size_t)NNODES * DD;        // N*D
    float* es     = bufB + (size_t)NNODES * DD;        // N
    float* edv    = es + NNODES;                       // N
    float* ealpha = edv + NNODES;                      // E
    float* w3s    = ealpha + EEDGES;                   // 256*256
    int*   rowptr = (int*)(w3s + DD * DD);             // N+1
    int*   cursor = rowptr + (NNODES + 1);             // N
    int*   colsrc = cursor + NNODES;                   // E
    int*   bsums  = colsrc + EEDGES;                   // SCAN_BLOCKS

    // --- CSR build (per call; harness poisons ws) ---
    zero_ints_k<<<(NNODES + 1 + 255) / 256, 256, 0, stream>>>(rowptr, NNODES + 1);
    hist_k<<<(EEDGES + 255) / 256, 256, 0, stream>>>(dst, rowptr);
    scan1_k<<<SCAN_BLOCKS, 256, 0, stream>>>(rowptr, bsums);
    scan2_k<<<1, 128, 0, stream>>>(bsums);
    scan3_k<<<SCAN_BLOCKS, 256, 0, stream>>>(rowptr, bsums);
    copy_cursor_k<<<(NNODES + 255) / 256, 256, 0, stream>>>(rowptr, cursor);
    scatter_k<<<(EEDGES + 255) / 256, 256, 0, stream>>>(src, dst, cursor, colsrc);
    w3sum_k<<<(DD * DD + 255) / 256, 256, 0, stream>>>(W3, w3s);

    dim3 ggrid(DD / 128, (NNODES + 63) / 64);
    const int nodeBlocks = (NNODES + 3) / 4;

    // h = (x @ W1) @ W2
    gemm_k<false><<<ggrid, 128, 0, stream>>>(x, W1, bufA, NNODES);
    gemm_k<false><<<ggrid, 128, 0, stream>>>(bufA, W2, bufB, NNODES);

    // 6 GAT layers; cur lives in bufB, hw in bufA each layer
    for (int l = 0; l < 6; ++l) {
        gemm_k<false><<<ggrid, 128, 0, stream>>>(bufB, Ws + (size_t)l * DD * DD, bufA, NNODES);
        dots_k<<<nodeBlocks, 256, 0, stream>>>(bufA, a_src + (size_t)l * DD, a_dst + (size_t)l * DD, es, edv);
        gat_agg_k<<<nodeBlocks, 256, 0, stream>>>(bufA, es, edv, rowptr, colsrc, ealpha,
                                                  bias + (size_t)l * DD, bufB);
    }

    // out = relu(h) @ (W3_top + W3_bot)
    gemm_k<true><<<ggrid, 128, 0, stream>>>(bufB, w3s, out, NNODES);
}

// Round 4
// 779.574 us; speedup vs baseline: 1.2122x; 1.1154x over previous
//
#include <hip/hip_runtime.h>

#define NNODES 20000
#define EEDGES 320000
#define DD     256
#define NEG_SLOPE 0.2f
#define SCAN_BLOCKS ((NNODES + 255) / 256)

// ---------------- CSR build ----------------

__global__ void zero_ints_k(int* __restrict__ p, int n) {
    int i = blockIdx.x * 256 + threadIdx.x;
    if (i < n) p[i] = 0;
}

__global__ void hist_k(const int* __restrict__ dst, int* __restrict__ rowptr) {
    int i = blockIdx.x * 256 + threadIdx.x;
    if (i < EEDGES) atomicAdd(&rowptr[dst[i] + 1], 1);
}

__global__ __launch_bounds__(256) void scan1_k(int* __restrict__ rowptr, int* __restrict__ bsums) {
    __shared__ int buf[256];
    int idx = blockIdx.x * 256 + threadIdx.x;
    int v = (idx < NNODES) ? rowptr[idx + 1] : 0;
    buf[threadIdx.x] = v;
    __syncthreads();
#pragma unroll
    for (int off = 1; off < 256; off <<= 1) {
        int t = (threadIdx.x >= (unsigned)off) ? buf[threadIdx.x - off] : 0;
        __syncthreads();
        buf[threadIdx.x] += t;
        __syncthreads();
    }
    if (idx < NNODES) rowptr[idx + 1] = buf[threadIdx.x];
    if (threadIdx.x == 255) bsums[blockIdx.x] = buf[255];
}

__global__ __launch_bounds__(128) void scan2_k(int* __restrict__ bsums) {
    __shared__ int buf[128];
    int v = (threadIdx.x < SCAN_BLOCKS) ? bsums[threadIdx.x] : 0;
    buf[threadIdx.x] = v;
    __syncthreads();
#pragma unroll
    for (int off = 1; off < 128; off <<= 1) {
        int t = (threadIdx.x >= (unsigned)off) ? buf[threadIdx.x - off] : 0;
        __syncthreads();
        buf[threadIdx.x] += t;
        __syncthreads();
    }
    if (threadIdx.x < SCAN_BLOCKS) bsums[threadIdx.x] = buf[threadIdx.x];
}

__global__ void scan3_k(int* __restrict__ rowptr, const int* __restrict__ bsums) {
    int idx = blockIdx.x * 256 + threadIdx.x;
    if (blockIdx.x > 0 && idx < NNODES) rowptr[idx + 1] += bsums[blockIdx.x - 1];
}

__global__ void copy_cursor_k(const int* __restrict__ rowptr, int* __restrict__ cursor) {
    int i = blockIdx.x * 256 + threadIdx.x;
    if (i < NNODES) cursor[i] = rowptr[i];
}

__global__ void scatter_k(const int* __restrict__ src, const int* __restrict__ dst,
                          int* __restrict__ cursor, int* __restrict__ colsrc) {
    int i = blockIdx.x * 256 + threadIdx.x;
    if (i < EEDGES) {
        int d = dst[i];
        int pos = atomicAdd(&cursor[d], 1);
        colsrc[pos] = src[i];
    }
}

// ---------------- W3 folding: concat(h,h)@W3 == relu(h)@(W3_top+W3_bot) ----------------

__global__ void w3sum_k(const float* __restrict__ W3, float* __restrict__ wsum) {
    int i = blockIdx.x * 256 + threadIdx.x;
    if (i < DD * DD) wsum[i] = W3[i] + W3[i + DD * DD];
}

// ---------------- fp32 GEMM: C[M,256] = act(A)[M,256] @ B[256,256] ----------------
// tile 64 rows x 64 cols, 128 threads, 8x4 micro-tile, software-pipelined.
// 1252 blocks -> ~4.9 blocks/CU for occupancy + balance.

template<bool RELU_A>
__global__ __launch_bounds__(128, 4) void gemm_k(const float* __restrict__ A,
                                                 const float* __restrict__ B,
                                                 float* __restrict__ C, int M) {
    __shared__ float As[16][68];   // transposed, padded: 2-way max on writes (free)
    __shared__ float Bs[16][64];
    const int t  = threadIdx.x;
    const int tx = t & 15;   // col group (4 cols)
    const int ty = t >> 4;   // row group (8 rows)
    const int rowBase = blockIdx.y * 64;
    const int colBase = blockIdx.x * 64;

    float acc[8][4];
#pragma unroll
    for (int i = 0; i < 8; ++i)
#pragma unroll
        for (int j = 0; j < 4; ++j) acc[i][j] = 0.f;

    const int ar = t >> 1;          // 0..63  A row in tile
    const int ac = (t & 1) * 8;     // 0 or 8 A k-offset
    const int br = t >> 4;          // 0..7   B k-row
    const int bc = (t & 15) * 4;    // 0..60  B col
    const int arow = rowBase + ar;

    float4 a0, a1, b0, b1;
    a0 = make_float4(0.f, 0.f, 0.f, 0.f);
    a1 = make_float4(0.f, 0.f, 0.f, 0.f);
    if (arow < M) {
        a0 = *(const float4*)(A + (size_t)arow * DD + ac);
        a1 = *(const float4*)(A + (size_t)arow * DD + ac + 4);
    }
    b0 = *(const float4*)(B + (size_t)(br    ) * DD + colBase + bc);
    b1 = *(const float4*)(B + (size_t)(br + 8) * DD + colBase + bc);

    for (int k0 = 0; k0 < DD; k0 += 16) {
        if (RELU_A) {
            a0.x = fmaxf(a0.x, 0.f); a0.y = fmaxf(a0.y, 0.f);
            a0.z = fmaxf(a0.z, 0.f); a0.w = fmaxf(a0.w, 0.f);
            a1.x = fmaxf(a1.x, 0.f); a1.y = fmaxf(a1.y, 0.f);
            a1.z = fmaxf(a1.z, 0.f); a1.w = fmaxf(a1.w, 0.f);
        }
        __syncthreads();
        As[ac + 0][ar] = a0.x; As[ac + 1][ar] = a0.y;
        As[ac + 2][ar] = a0.z; As[ac + 3][ar] = a0.w;
        As[ac + 4][ar] = a1.x; As[ac + 5][ar] = a1.y;
        As[ac + 6][ar] = a1.z; As[ac + 7][ar] = a1.w;
        *(float4*)&Bs[br    ][bc] = b0;
        *(float4*)&Bs[br + 8][bc] = b1;
        __syncthreads();

        if (k0 + 16 < DD) {
            int kn = k0 + 16;
            if (arow < M) {
                a0 = *(const float4*)(A + (size_t)arow * DD + kn + ac);
                a1 = *(const float4*)(A + (size_t)arow * DD + kn + ac + 4);
            }
            b0 = *(const float4*)(B + (size_t)(kn + br    ) * DD + colBase + bc);
            b1 = *(const float4*)(B + (size_t)(kn + br + 8) * DD + colBase + bc);
        }

#pragma unroll
        for (int kk = 0; kk < 16; ++kk) {
            float a[8], b[4];
            *(float4*)&a[0] = *(const float4*)&As[kk][ty * 8];
            *(float4*)&a[4] = *(const float4*)&As[kk][ty * 8 + 4];
            *(float4*)&b[0] = *(const float4*)&Bs[kk][tx * 4];
#pragma unroll
            for (int i = 0; i < 8; ++i)
#pragma unroll
                for (int j = 0; j < 4; ++j)
                    acc[i][j] = fmaf(a[i], b[j], acc[i][j]);
        }
    }

#pragma unroll
    for (int i = 0; i < 8; ++i) {
        int r = rowBase + ty * 8 + i;
        if (r < M) {
            float4 o = make_float4(acc[i][0], acc[i][1], acc[i][2], acc[i][3]);
            *(float4*)(C + (size_t)r * DD + colBase + tx * 4) = o;
        }
    }
}

// ---------------- per-node attention dots ----------------

__global__ __launch_bounds__(256) void dots_k(const float* __restrict__ hw,
                                              const float* __restrict__ asrc,
                                              const float* __restrict__ adst,
                                              float* __restrict__ es, float* __restrict__ ed) {
    int wave = threadIdx.x >> 6;
    int lane = threadIdx.x & 63;
    int node = blockIdx.x * 4 + wave;
    if (node >= NNODES) return;
    float4 v = *(const float4*)(hw + (size_t)node * DD + lane * 4);
    float4 a = *(const float4*)(asrc + lane * 4);
    float4 b = *(const float4*)(adst + lane * 4);
    float s = v.x * a.x + v.y * a.y + v.z * a.z + v.w * a.w;
    float d = v.x * b.x + v.y * b.y + v.z * b.z + v.w * b.w;
#pragma unroll
    for (int off = 32; off; off >>= 1) {
        s += __shfl_xor(s, off);
        d += __shfl_xor(d, off);
    }
    if (lane == 0) { es[node] = s; ed[node] = d; }
}

// ---------------- fused segment softmax + weighted aggregation (one wave per node) ----
// Fast path deg<=64: scores in registers, alpha broadcast by shuffle, no global scratch,
// phase C unrolled x4 with 4 independent accumulators for memory-level parallelism.

__global__ __launch_bounds__(256) void gat_agg_k(const float* __restrict__ hw,
                                                 const float* __restrict__ es,
                                                 const float* __restrict__ ed,
                                                 const int* __restrict__ rowptr,
                                                 const int* __restrict__ colsrc,
                                                 float* __restrict__ ealpha,
                                                 const float* __restrict__ bias,
                                                 float* __restrict__ hout) {
    int wave = threadIdx.x >> 6;
    int lane = threadIdx.x & 63;
    int node = blockIdx.x * 4 + wave;
    if (node >= NNODES) return;
    int start = rowptr[node], end = rowptr[node + 1];
    int deg = end - start;
    float edd = ed[node];

    float4 acc0 = make_float4(0.f, 0.f, 0.f, 0.f);
    float4 acc1 = acc0, acc2 = acc0, acc3 = acc0;

    if (deg <= 64) {
        if (deg > 0) {
            int j = start + lane;
            bool valid = j < end;
            int msrc = valid ? colsrc[j] : 0;
            float e = valid ? es[msrc] + edd : -INFINITY;
            e = fmaxf(e, NEG_SLOPE * e);                  // leaky_relu
            float mx = e;
#pragma unroll
            for (int off = 32; off; off >>= 1) mx = fmaxf(mx, __shfl_xor(mx, off));
            float ee = valid ? expf(e - mx) : 0.f;
            float sum = ee;
#pragma unroll
            for (int off = 32; off; off >>= 1) sum += __shfl_xor(sum, off);
            float w = ee / sum;                            // this lane's alpha

            int j2 = 0;
            for (; j2 + 4 <= deg; j2 += 4) {
                int   s0 = __shfl(msrc, j2 + 0), s1 = __shfl(msrc, j2 + 1);
                int   s2 = __shfl(msrc, j2 + 2), s3 = __shfl(msrc, j2 + 3);
                float w0 = __shfl(w, j2 + 0), w1 = __shfl(w, j2 + 1);
                float w2 = __shfl(w, j2 + 2), w3 = __shfl(w, j2 + 3);
                float4 v0 = *(const float4*)(hw + (size_t)s0 * DD + lane * 4);
                float4 v1 = *(const float4*)(hw + (size_t)s1 * DD + lane * 4);
                float4 v2 = *(const float4*)(hw + (size_t)s2 * DD + lane * 4);
                float4 v3 = *(const float4*)(hw + (size_t)s3 * DD + lane * 4);
                acc0.x = fmaf(w0, v0.x, acc0.x); acc0.y = fmaf(w0, v0.y, acc0.y);
                acc0.z = fmaf(w0, v0.z, acc0.z); acc0.w = fmaf(w0, v0.w, acc0.w);
                acc1.x = fmaf(w1, v1.x, acc1.x); acc1.y = fmaf(w1, v1.y, acc1.y);
                acc1.z = fmaf(w1, v1.z, acc1.z); acc1.w = fmaf(w1, v1.w, acc1.w);
                acc2.x = fmaf(w2, v2.x, acc2.x); acc2.y = fmaf(w2, v2.y, acc2.y);
                acc2.z = fmaf(w2, v2.z, acc2.z); acc2.w = fmaf(w2, v2.w, acc2.w);
                acc3.x = fmaf(w3, v3.x, acc3.x); acc3.y = fmaf(w3, v3.y, acc3.y);
                acc3.z = fmaf(w3, v3.z, acc3.z); acc3.w = fmaf(w3, v3.w, acc3.w);
            }
            for (; j2 < deg; ++j2) {
                int   s0 = __shfl(msrc, j2);
                float w0 = __shfl(w, j2);
                float4 v0 = *(const float4*)(hw + (size_t)s0 * DD + lane * 4);
                acc0.x = fmaf(w0, v0.x, acc0.x); acc0.y = fmaf(w0, v0.y, acc0.y);
                acc0.z = fmaf(w0, v0.z, acc0.z); acc0.w = fmaf(w0, v0.w, acc0.w);
            }
        }
    } else {
        // rare fallback: deg > 64, use global scratch
        float mx = -INFINITY;
        for (int j = start + lane; j < end; j += 64) {
            float e = es[colsrc[j]] + edd;
            e = fmaxf(e, NEG_SLOPE * e);
            mx = fmaxf(mx, e);
        }
#pragma unroll
        for (int off = 32; off; off >>= 1) mx = fmaxf(mx, __shfl_xor(mx, off));
        float sum = 0.f;
        for (int j = start + lane; j < end; j += 64) {
            float e = es[colsrc[j]] + edd;
            e = fmaxf(e, NEG_SLOPE * e);
            float ee = expf(e - mx);
            ealpha[j] = ee;
            sum += ee;
        }
#pragma unroll
        for (int off = 32; off; off >>= 1) sum += __shfl_xor(sum, off);
        float inv = 1.f / sum;
        int j = start;
        for (; j + 4 <= end; j += 4) {
            int s0 = colsrc[j], s1 = colsrc[j + 1], s2 = colsrc[j + 2], s3 = colsrc[j + 3];
            float w0 = ealpha[j] * inv, w1 = ealpha[j + 1] * inv;
            float w2 = ealpha[j + 2] * inv, w3 = ealpha[j + 3] * inv;
            float4 v0 = *(const float4*)(hw + (size_t)s0 * DD + lane * 4);
            float4 v1 = *(const float4*)(hw + (size_t)s1 * DD + lane * 4);
            float4 v2 = *(const float4*)(hw + (size_t)s2 * DD + lane * 4);
            float4 v3 = *(const float4*)(hw + (size_t)s3 * DD + lane * 4);
            acc0.x = fmaf(w0, v0.x, acc0.x); acc0.y = fmaf(w0, v0.y, acc0.y);
            acc0.z = fmaf(w0, v0.z, acc0.z); acc0.w = fmaf(w0, v0.w, acc0.w);
            acc1.x = fmaf(w1, v1.x, acc1.x); acc1.y = fmaf(w1, v1.y, acc1.y);
            acc1.z = fmaf(w1, v1.z, acc1.z); acc1.w = fmaf(w1, v1.w, acc1.w);
            acc2.x = fmaf(w2, v2.x, acc2.x); acc2.y = fmaf(w2, v2.y, acc2.y);
            acc2.z = fmaf(w2, v2.z, acc2.z); acc2.w = fmaf(w2, v2.w, acc2.w);
            acc3.x = fmaf(w3, v3.x, acc3.x); acc3.y = fmaf(w3, v3.y, acc3.y);
            acc3.z = fmaf(w3, v3.z, acc3.z); acc3.w = fmaf(w3, v3.w, acc3.w);
        }
        for (; j < end; ++j) {
            int s0 = colsrc[j];
            float w0 = ealpha[j] * inv;
            float4 v0 = *(const float4*)(hw + (size_t)s0 * DD + lane * 4);
            acc0.x = fmaf(w0, v0.x, acc0.x); acc0.y = fmaf(w0, v0.y, acc0.y);
            acc0.z = fmaf(w0, v0.z, acc0.z); acc0.w = fmaf(w0, v0.w, acc0.w);
        }
    }

    acc0.x += acc1.x; acc0.y += acc1.y; acc0.z += acc1.z; acc0.w += acc1.w;
    acc2.x += acc3.x; acc2.y += acc3.y; acc2.z += acc3.z; acc2.w += acc3.w;
    acc0.x += acc2.x; acc0.y += acc2.y; acc0.z += acc2.z; acc0.w += acc2.w;
    float4 b4 = *(const float4*)(bias + lane * 4);
    acc0.x += b4.x; acc0.y += b4.y; acc0.z += b4.z; acc0.w += b4.w;
    *(float4*)(hout + (size_t)node * DD + lane * 4) = acc0;
}

// ---------------- driver ----------------

extern "C" void kernel_launch(void* const* d_in, const int* in_sizes, int n_in,
                              void* d_out, int out_size, void* d_ws, size_t ws_size,
                              hipStream_t stream) {
    const float* x     = (const float*)d_in[0];
    const int*   ei    = (const int*)d_in[1];     // [2,E]: first E = src, next E = dst
    const float* W1    = (const float*)d_in[2];
    const float* W2    = (const float*)d_in[3];
    const float* Ws    = (const float*)d_in[4];   // [6,256,256]
    const float* a_src = (const float*)d_in[5];   // [6,256]
    const float* a_dst = (const float*)d_in[6];
    const float* bias  = (const float*)d_in[7];   // [6,256]
    const float* W3    = (const float*)d_in[8];   // [512,256]
    float* out = (float*)d_out;

    const int* src = ei;
    const int* dst = ei + EEDGES;

    // workspace carve-up
    float* bufA   = (float*)d_ws;                      // N*D
    float* bufB   = bufA + (size_t)NNODES * DD;        // N*D
    float* es     = bufB + (size_t)NNODES * DD;        // N
    float* edv    = es + NNODES;                       // N
    float* ealpha = edv + NNODES;                      // E
    float* w3s    = ealpha + EEDGES;                   // 256*256
    int*   rowptr = (int*)(w3s + DD * DD);             // N+1
    int*   cursor = rowptr + (NNODES + 1);             // N
    int*   colsrc = cursor + NNODES;                   // E
    int*   bsums  = colsrc + EEDGES;                   // SCAN_BLOCKS

    // --- CSR build (per call; harness poisons ws) ---
    zero_ints_k<<<(NNODES + 1 + 255) / 256, 256, 0, stream>>>(rowptr, NNODES + 1);
    hist_k<<<(EEDGES + 255) / 256, 256, 0, stream>>>(dst, rowptr);
    scan1_k<<<SCAN_BLOCKS, 256, 0, stream>>>(rowptr, bsums);
    scan2_k<<<1, 128, 0, stream>>>(bsums);
    scan3_k<<<SCAN_BLOCKS, 256, 0, stream>>>(rowptr, bsums);
    copy_cursor_k<<<(NNODES + 255) / 256, 256, 0, stream>>>(rowptr, cursor);
    scatter_k<<<(EEDGES + 255) / 256, 256, 0, stream>>>(src, dst, cursor, colsrc);
    w3sum_k<<<(DD * DD + 255) / 256, 256, 0, stream>>>(W3, w3s);

    dim3 ggrid(DD / 64, (NNODES + 63) / 64);
    const int nodeBlocks = (NNODES + 3) / 4;

    // h = (x @ W1) @ W2
    gemm_k<false><<<ggrid, 128, 0, stream>>>(x, W1, bufA, NNODES);
    gemm_k<false><<<ggrid, 128, 0, stream>>>(bufA, W2, bufB, NNODES);

    // 6 GAT layers; cur lives in bufB, hw in bufA each layer
    for (int l = 0; l < 6; ++l) {
        gemm_k<false><<<ggrid, 128, 0, stream>>>(bufB, Ws + (size_t)l * DD * DD, bufA, NNODES);
        dots_k<<<nodeBlocks, 256, 0, stream>>>(bufA, a_src + (size_t)l * DD, a_dst + (size_t)l * DD, es, edv);
        gat_agg_k<<<nodeBlocks, 256, 0, stream>>>(bufA, es, edv, rowptr, colsrc, ealpha,
                                                  bias + (size_t)l * DD, bufB);
    }

    // out = relu(h) @ (W3_top + W3_bot)
    gemm_k<true><<<ggrid, 128, 0, stream>>>(bufB, w3s, out, NNODES);
}